// Round 1
// baseline (10302.049 us; speedup 1.0000x reference)
//
#include <hip/hip_runtime.h>
#include <math.h>

#define NP 65536
#define HD 128
#define TSTEPS 50

__device__ __forceinline__ float fast_tanh(float x) {
    float xc = fminf(fmaxf(x, -15.0f), 15.0f);
    // tanh(x) = 1 - 2/(exp(2x)+1);  exp(2x) = 2^(x * 2/ln2)
    float e = __builtin_amdgcn_exp2f(xc * 2.8853900817779268f);
    return 1.0f - 2.0f * __builtin_amdgcn_rcpf(e + 1.0f);
}

// ---------------------------------------------------------------------------
// Kernel 1: per-step tables.
//   tembW[i][j] = b1[j] + sum_m sin(2pi t f_m) W1[130+m][j] + cos(...) W1[146+m][j]
//   tV[i][j]    = t_i * V1[130][j] + c1[j]
//   dtv[i] = t_{i+1}-t_i ;  nsv[i] = softplus(log_diff)*(1-t_i)*sqrt(max(dt,1e-12))
// ---------------------------------------------------------------------------
__global__ __launch_bounds__(128) void prep_kernel(
    const float* __restrict__ times, const float* __restrict__ freqs,
    const float* __restrict__ log_diff,
    const float* __restrict__ W1, const float* __restrict__ b1,
    const float* __restrict__ V1, const float* __restrict__ c1,
    float* __restrict__ tembW, float* __restrict__ tV,
    float* __restrict__ dtv, float* __restrict__ nsv)
{
    int j = threadIdx.x;  // 128 threads, one per hidden unit
    float ld = log_diff[0];
    float gb = (ld > 20.0f) ? ld : log1pf(expf(ld));  // softplus
    for (int i = 0; i < TSTEPS; ++i) {
        float t  = times[i];
        float dt = times[i + 1] - t;
        float acc = b1[j];
        #pragma unroll
        for (int m = 0; m < 16; ++m) {
            float a = 6.283185307179586f * t * freqs[m];
            float sn, cs;
            sincosf(a, &sn, &cs);
            acc = fmaf(sn, W1[(130 + m) * HD + j], acc);
            acc = fmaf(cs, W1[(146 + m) * HD + j], acc);
        }
        tembW[i * HD + j] = acc;
        tV[i * HD + j] = fmaf(t, V1[130 * HD + j], c1[j]);
        if (j == 0) {
            dtv[i] = dt;
            nsv[i] = gb * (1.0f - t) * sqrtf(fmaxf(dt, 1e-12f));
        }
    }
}

// ---------------------------------------------------------------------------
// Kernel 2: step-invariant ctx projections, stored TRANSPOSED [128][NP] so the
// main loop reads them coalesced.  postT[j][n] = sum_c pctx[n][c] * W1[2+c][j]
// ---------------------------------------------------------------------------
__global__ __launch_bounds__(128) void ctxproj_kernel(
    const float* __restrict__ pctx, const float* __restrict__ cctx,
    const float* __restrict__ W1, const float* __restrict__ V1,
    float* __restrict__ postT, float* __restrict__ cnfT)
{
    int n = blockIdx.x * 128 + threadIdx.x;
    for (int pass = 0; pass < 2; ++pass) {
        const float* __restrict__ ctx = pass ? cctx : pctx;
        const float* __restrict__ W   = pass ? V1 : W1;
        float* __restrict__ outT      = pass ? cnfT : postT;
        const float* crow = ctx + (size_t)n * 128;
        for (int jc = 0; jc < 4; ++jc) {
            float acc[32];
            #pragma unroll
            for (int jj = 0; jj < 32; ++jj) acc[jj] = 0.0f;
            for (int cc = 0; cc < 4; ++cc) {
                float xv[32];
                #pragma unroll
                for (int kk = 0; kk < 32; ++kk) xv[kk] = crow[cc * 32 + kk];
                #pragma unroll
                for (int kk = 0; kk < 32; ++kk) {
                    const float* wrow = W + (size_t)(2 + cc * 32 + kk) * HD + jc * 32;
                    #pragma unroll
                    for (int jj = 0; jj < 32; ++jj)
                        acc[jj] = fmaf(xv[kk], wrow[jj], acc[jj]);
                }
            }
            #pragma unroll
            for (int jj = 0; jj < 32; ++jj)
                outT[(size_t)(jc * 32 + jj) * NP + n] = acc[jj];
        }
    }
}

// ---------------------------------------------------------------------------
// One MLP evaluation for this thread's particle.  Layer-1 activations go to
// LDS (column tid, thread-private -> no barriers).  Layer 2 is 32x32 register
// blocked; weight indices are wave-uniform -> scalar loads.
// ---------------------------------------------------------------------------
template <bool IS_TANH>
__device__ __forceinline__ void mlp_eval(
    float zx, float zy, int n, int tid,
    const float* __restrict__ projT, const float* __restrict__ trow,
    const float* __restrict__ Wz,   // rows 0,1 of W1/V1 (z weights)
    const float* __restrict__ W2, const float* __restrict__ b2,
    const float* __restrict__ W3, const float* __restrict__ b3,
    float* __restrict__ lds, float& ox, float& oy)
{
    // layer 1
    for (int k4 = 0; k4 < 4; ++k4) {
        #pragma unroll
        for (int kk = 0; kk < 32; ++kk) {
            int k = k4 * 32 + kk;
            float v = projT[(size_t)k * NP + n];
            v += trow[k];
            v = fmaf(zx, Wz[k], v);
            v = fmaf(zy, Wz[HD + k], v);
            lds[k * 128 + tid] = IS_TANH ? fast_tanh(v) : fmaxf(v, 0.0f);
        }
    }
    // layers 2+3
    ox = b3[0];
    oy = b3[1];
    for (int jc = 0; jc < 4; ++jc) {
        float acc[32];
        #pragma unroll
        for (int jj = 0; jj < 32; ++jj) acc[jj] = b2[jc * 32 + jj];
        for (int kc = 0; kc < 4; ++kc) {
            float hh[32];
            #pragma unroll
            for (int kk = 0; kk < 32; ++kk) hh[kk] = lds[(kc * 32 + kk) * 128 + tid];
            #pragma unroll
            for (int kk = 0; kk < 32; ++kk) {
                const float* wrow = W2 + (size_t)(kc * 32 + kk) * HD + jc * 32;
                #pragma unroll
                for (int jj = 0; jj < 32; ++jj)
                    acc[jj] = fmaf(hh[kk], wrow[jj], acc[jj]);
            }
        }
        #pragma unroll
        for (int jj = 0; jj < 32; ++jj) {
            float h2 = IS_TANH ? fast_tanh(acc[jj]) : fmaxf(acc[jj], 0.0f);
            ox = fmaf(h2, W3[(jc * 32 + jj) * 2 + 0], ox);
            oy = fmaf(h2, W3[(jc * 32 + jj) * 2 + 1], oy);
        }
    }
}

// ---------------------------------------------------------------------------
// Kernel 3: the 50-step SDE integration, one thread per particle.
// ---------------------------------------------------------------------------
__global__ __launch_bounds__(128) void sde_kernel(
    const float* __restrict__ z0, const float* __restrict__ xi,
    const float* __restrict__ W1, const float* __restrict__ W2,
    const float* __restrict__ b2, const float* __restrict__ W3,
    const float* __restrict__ b3,
    const float* __restrict__ V1, const float* __restrict__ V2,
    const float* __restrict__ c2, const float* __restrict__ V3,
    const float* __restrict__ c3,
    const float* __restrict__ postT, const float* __restrict__ cnfT,
    const float* __restrict__ tembW, const float* __restrict__ tV,
    const float* __restrict__ dtv, const float* __restrict__ nsv,
    float* __restrict__ out)
{
    __shared__ float h1s[128 * 128];   // 64 KB: [k][tid]
    int tid = threadIdx.x;
    int n = blockIdx.x * 128 + tid;

    const float2* z02 = (const float2*)z0;
    const float2* xi2 = (const float2*)xi;
    float2* out2 = (float2*)out;

    float2 z = z02[n];
    out2[n] = z;  // traj[0] = z0

    for (int i = 0; i < TSTEPS; ++i) {
        float cx, cy, px, py;
        mlp_eval<true >(z.x, z.y, n, tid, cnfT,  tV    + i * HD, V1, V2, c2, V3, c3, h1s, cx, cy);
        mlp_eval<false>(z.x, z.y, n, tid, postT, tembW + i * HD, W1, W2, b2, W3, b3, h1s, px, py);
        float dt = dtv[i];
        float ns = nsv[i];
        float2 xv = xi2[(size_t)i * NP + n];
        z.x = fmaf(cx + px, dt, z.x) + xv.x * ns;
        z.y = fmaf(cy + py, dt, z.y) + xv.y * ns;
        out2[(size_t)(i + 1) * NP + n] = z;
    }
}

extern "C" void kernel_launch(void* const* d_in, const int* in_sizes, int n_in,
                              void* d_out, int out_size, void* d_ws, size_t ws_size,
                              hipStream_t stream)
{
    const float* z0    = (const float*)d_in[0];
    const float* pctx  = (const float*)d_in[1];
    const float* cctx  = (const float*)d_in[2];
    const float* times = (const float*)d_in[3];
    const float* xi    = (const float*)d_in[4];
    const float* freqs = (const float*)d_in[5];
    const float* logd  = (const float*)d_in[6];
    const float* W1 = (const float*)d_in[7];
    const float* b1 = (const float*)d_in[8];
    const float* W2 = (const float*)d_in[9];
    const float* b2 = (const float*)d_in[10];
    const float* W3 = (const float*)d_in[11];
    const float* b3 = (const float*)d_in[12];
    const float* V1 = (const float*)d_in[13];
    const float* c1 = (const float*)d_in[14];
    const float* V2 = (const float*)d_in[15];
    const float* c2 = (const float*)d_in[16];
    const float* V3 = (const float*)d_in[17];
    const float* c3 = (const float*)d_in[18];

    float* ws    = (float*)d_ws;
    float* postT = ws;                                  // [128][NP]
    float* cnfT  = ws + (size_t)HD * NP;                // [128][NP]
    float* tembW = ws + (size_t)2 * HD * NP;            // [50][128]
    float* tV    = tembW + TSTEPS * HD;                 // [50][128]
    float* dtv   = tV + TSTEPS * HD;                    // [50]
    float* nsv   = dtv + 64;                            // [50]

    prep_kernel<<<1, 128, 0, stream>>>(times, freqs, logd, W1, b1, V1, c1,
                                       tembW, tV, dtv, nsv);
    ctxproj_kernel<<<NP / 128, 128, 0, stream>>>(pctx, cctx, W1, V1, postT, cnfT);
    sde_kernel<<<NP / 128, 128, 0, stream>>>(z0, xi, W1, W2, b2, W3, b3,
                                             V1, V2, c2, V3, c3,
                                             postT, cnfT, tembW, tV, dtv, nsv,
                                             (float*)d_out);
}

// Round 2
// 6033.951 us; speedup vs baseline: 1.7073x; 1.7073x over previous
//
#include <hip/hip_runtime.h>
#include <math.h>

#define NP 65536
#define HD 128
#define TSTEPS 50

typedef short bf16x8 __attribute__((ext_vector_type(8)));
typedef float f32x4 __attribute__((ext_vector_type(4)));

__device__ __forceinline__ short f2bf(float f) {
    union { float f; unsigned u; } v; v.f = f;
    unsigned r = v.u + 0x7fffu + ((v.u >> 16) & 1u);
    return (short)(r >> 16);
}
__device__ __forceinline__ unsigned packbf(float a, float b) {
    return ((unsigned)(unsigned short)f2bf(a)) | (((unsigned)(unsigned short)f2bf(b)) << 16);
}
__device__ __forceinline__ float bflo(unsigned u){ union{unsigned u; float f;} v; v.u = u << 16; return v.f; }
__device__ __forceinline__ float bfhi(unsigned u){ union{unsigned u; float f;} v; v.u = u & 0xffff0000u; return v.f; }

__device__ __forceinline__ float fast_tanh(float x) {
    // exp2-based; saturates correctly for large |x| without clamps
    float e = __builtin_amdgcn_exp2f(x * 2.8853900817779268f);
    return 1.0f - 2.0f * __builtin_amdgcn_rcpf(e + 1.0f);
}

// ---------------------------------------------------------------------------
// Per-step tables: tembW[i][j] = b1[j] + Σ sin/cos(2π t f)·W1[temb rows][j]
//                  tV[i][j]    = c1[j] + t·V1[130][j]
// ---------------------------------------------------------------------------
__global__ __launch_bounds__(128) void prep_kernel(
    const float* __restrict__ times, const float* __restrict__ freqs,
    const float* __restrict__ log_diff,
    const float* __restrict__ W1, const float* __restrict__ b1,
    const float* __restrict__ V1, const float* __restrict__ c1,
    float* __restrict__ tembW, float* __restrict__ tV,
    float* __restrict__ dtv, float* __restrict__ nsv)
{
    int j = threadIdx.x;
    float ld = log_diff[0];
    float gb = (ld > 20.0f) ? ld : log1pf(expf(ld));  // softplus
    for (int i = 0; i < TSTEPS; ++i) {
        float t  = times[i];
        float dt = times[i + 1] - t;
        float acc = b1[j];
        #pragma unroll
        for (int m = 0; m < 16; ++m) {
            float a = 6.283185307179586f * t * freqs[m];
            float sn, cs;
            sincosf(a, &sn, &cs);
            acc = fmaf(sn, W1[(130 + m) * HD + j], acc);
            acc = fmaf(cs, W1[(146 + m) * HD + j], acc);
        }
        tembW[i * HD + j] = acc;
        tV[i * HD + j] = fmaf(t, V1[130 * HD + j], c1[j]);
        if (j == 0) {
            dtv[i] = dt;
            nsv[i] = gb * (1.0f - t) * sqrtf(fmaxf(dt, 1e-12f));
        }
    }
}

// ---------------------------------------------------------------------------
// Pack 4 weight matrices (W1ctx, V1ctx, W2, V2) into bf16 B-fragment order:
// frag idx = ((jt*4+kt)*4+q)*16+c, element j;  k = kt*32+q*8+j, n = jt*16+c.
// ---------------------------------------------------------------------------
__global__ __launch_bounds__(256) void pack_kernel(
    const float* __restrict__ W1, const float* __restrict__ V1,
    const float* __restrict__ W2, const float* __restrict__ V2,
    short* __restrict__ packed)
{
    int gi = blockIdx.x * 256 + threadIdx.x;   // 0..65535
    int mat = gi >> 14;
    int s = gi & 16383;
    int j  = s & 7;
    int cc = (s >> 3) & 15;
    int qq = (s >> 7) & 3;
    int kt = (s >> 9) & 3;
    int jt = (s >> 11) & 7;
    int k = kt * 32 + qq * 8 + j;
    int n = jt * 16 + cc;
    float v;
    if      (mat == 0) v = W1[(2 + k) * HD + n];
    else if (mat == 1) v = V1[(2 + k) * HD + n];
    else if (mat == 2) v = W2[k * HD + n];
    else               v = V2[k * HD + n];
    packed[gi] = f2bf(v);
}

// ---------------------------------------------------------------------------
// Persistent SDE kernel: wave owns 16 particles (M=16 MFMA row tile) for all
// 50 steps. Lane computes H1 directly in A-operand layout (m=lane&15,
// k=quad*8+j) -> no transform between layer1 and layer2 MFMA.
// ---------------------------------------------------------------------------
__global__ __launch_bounds__(256, 2) void sde_kernel(
    const float* __restrict__ z0, const float* __restrict__ pctx,
    const float* __restrict__ cctx, const float* __restrict__ xi,
    const short* __restrict__ packedW,
    const float* __restrict__ W1, const float* __restrict__ V1,
    const float* __restrict__ b2, const float* __restrict__ c2,
    const float* __restrict__ W3, const float* __restrict__ b3,
    const float* __restrict__ V3, const float* __restrict__ c3,
    const float* __restrict__ tembW, const float* __restrict__ tV,
    const float* __restrict__ dtv, const float* __restrict__ nsv,
    float* __restrict__ out)
{
    __shared__ char smem[67584];            // max(64KB frags, 2*64*132*4 staging)
    float* stg = (float*)smem;
    const bf16x8* ldsF = (const bf16x8*)smem;

    int tid = threadIdx.x;
    int lane = tid & 63, wv = tid >> 6;
    int q = lane >> 4, c = lane & 15;
    int m0 = blockIdx.x * 64 + wv * 16;     // wave's 16-row base
    int mrow = m0 + c;                      // this lane's A-layout row

    // ---- phase 1: W1ctx/V1ctx fragments -> LDS (coalesced copy) ----
    {
        const uint4* src = (const uint4*)packedW;   // mats 0,1 = 64 KB
        uint4* dst = (uint4*)smem;
        #pragma unroll
        for (int i = 0; i < 16; ++i) dst[i * 256 + tid] = src[i * 256 + tid];
    }
    __syncthreads();

    // ---- ctx A-fragments ----
    bf16x8 pf[4], cf[4];
    #pragma unroll
    for (int kt = 0; kt < 4; ++kt) {
        const float4* p4 = (const float4*)(pctx + (size_t)mrow * HD + kt * 32 + q * 8);
        float4 a = p4[0], b = p4[1];
        bf16x8 t;
        t[0]=f2bf(a.x); t[1]=f2bf(a.y); t[2]=f2bf(a.z); t[3]=f2bf(a.w);
        t[4]=f2bf(b.x); t[5]=f2bf(b.y); t[6]=f2bf(b.z); t[7]=f2bf(b.w);
        pf[kt] = t;
        const float4* c4 = (const float4*)(cctx + (size_t)mrow * HD + kt * 32 + q * 8);
        float4 e = c4[0], d = c4[1];
        bf16x8 u;
        u[0]=f2bf(e.x); u[1]=f2bf(e.y); u[2]=f2bf(e.z); u[3]=f2bf(e.w);
        u[4]=f2bf(d.x); u[5]=f2bf(d.y); u[6]=f2bf(d.z); u[7]=f2bf(d.w);
        cf[kt] = u;
    }

    // ---- ctx projection MFMAs (step-invariant) ----
    f32x4 accP[8], accC[8];
    #pragma unroll
    for (int jt = 0; jt < 8; ++jt) {
        f32x4 ap = {0.f,0.f,0.f,0.f}, ac = {0.f,0.f,0.f,0.f};
        #pragma unroll
        for (int kt = 0; kt < 4; ++kt) {
            int fi = ((jt * 4 + kt) * 4 + q) * 16 + c;
            ap = __builtin_amdgcn_mfma_f32_16x16x32_bf16(pf[kt], ldsF[fi], ap, 0, 0, 0);
            ac = __builtin_amdgcn_mfma_f32_16x16x32_bf16(cf[kt], ldsF[2048 + fi], ac, 0, 0, 0);
        }
        accP[jt] = ap; accC[jt] = ac;
    }
    __syncthreads();

    // ---- C-layout -> A-layout round trip through LDS (once) ----
    #pragma unroll
    for (int jt = 0; jt < 8; ++jt)
        #pragma unroll
        for (int r = 0; r < 4; ++r) {
            stg[(wv * 16 + q * 4 + r) * 132 + jt * 16 + c]        = accP[jt][r];
            stg[8448 + (wv * 16 + q * 4 + r) * 132 + jt * 16 + c] = accC[jt][r];
        }
    __syncthreads();
    unsigned projP[16], projC[16];
    #pragma unroll
    for (int kt = 0; kt < 4; ++kt) {
        const float4* rp = (const float4*)(stg + (wv * 16 + c) * 132 + kt * 32 + q * 8);
        float4 a = rp[0], b = rp[1];
        projP[kt*4+0] = packbf(a.x, a.y); projP[kt*4+1] = packbf(a.z, a.w);
        projP[kt*4+2] = packbf(b.x, b.y); projP[kt*4+3] = packbf(b.z, b.w);
        const float4* rc = (const float4*)(stg + 8448 + (wv * 16 + c) * 132 + kt * 32 + q * 8);
        float4 e = rc[0], d = rc[1];
        projC[kt*4+0] = packbf(e.x, e.y); projC[kt*4+1] = packbf(e.z, e.w);
        projC[kt*4+2] = packbf(d.x, d.y); projC[kt*4+3] = packbf(d.z, d.w);
    }
    __syncthreads();

    // ---- phase 3: W2/V2 fragments -> LDS (resident for all 50 steps) ----
    {
        const uint4* src = (const uint4*)(packedW + 32768);  // mats 2,3
        uint4* dst = (uint4*)smem;
        #pragma unroll
        for (int i = 0; i < 16; ++i) dst[i * 256 + tid] = src[i * 256 + tid];
    }
    __syncthreads();

    // ---- per-lane constants ----
    unsigned wzP[32], wzC[32];   // packed (row0,row1) z-weights per k
    #pragma unroll
    for (int kt = 0; kt < 4; ++kt)
        #pragma unroll
        for (int jj = 0; jj < 8; ++jj) {
            int k = kt * 32 + q * 8 + jj;
            wzP[kt*8+jj] = packbf(W1[k], W1[HD + k]);
            wzC[kt*8+jj] = packbf(V1[k], V1[HD + k]);
        }
    float b2r[8], c2r[8]; float2 w3r[8], v3r[8];
    #pragma unroll
    for (int jt = 0; jt < 8; ++jt) {
        int n = jt * 16 + c;
        b2r[jt] = b2[n]; c2r[jt] = c2[n];
        w3r[jt] = ((const float2*)W3)[n];
        v3r[jt] = ((const float2*)V3)[n];
    }
    float b3x = b3[0] + c3[0], b3y = b3[1] + c3[1];

    const float2* z02 = (const float2*)z0;
    const float2* xi2 = (const float2*)xi;
    float2* out2 = (float2*)out;

    float2 zi = z02[mrow];
    float zx = zi.x, zy = zi.y;          // z for row m = c (A-layout row)
    int myrow = q * 4 + (c & 3);         // row this lane writes (if c<4)
    {
        float t0x = __shfl(zx, myrow), t0y = __shfl(zy, myrow);
        if (c < 4) out2[m0 + myrow] = make_float2(t0x, t0y);
    }

    for (int i = 0; i < TSTEPS; ++i) {
        float dt = dtv[i], ns = nsv[i];
        float px[4], py[4];
        #pragma unroll
        for (int r = 0; r < 4; ++r) { px[r] = b3x; py[r] = b3y; }

        // ===== cnf MLP: tanh, V-weights (LDS slot 1) =====
        bf16x8 af[4];
        #pragma unroll
        for (int kt = 0; kt < 4; ++kt) {
            const float4* t4 = (const float4*)(tV + i * HD + kt * 32 + q * 8);
            float4 ta = t4[0], tb = t4[1];
            float tv8[8] = {ta.x,ta.y,ta.z,ta.w,tb.x,tb.y,tb.z,tb.w};
            bf16x8 t;
            #pragma unroll
            for (int jj = 0; jj < 8; ++jj) {
                unsigned pp = projC[kt*4 + (jj >> 1)];
                float pv = (jj & 1) ? bfhi(pp) : bflo(pp);
                unsigned wz = wzC[kt*8+jj];
                float v = pv + tv8[jj] + zx * bflo(wz) + zy * bfhi(wz);
                t[jj] = f2bf(fast_tanh(v));
            }
            af[kt] = t;
        }
        #pragma unroll
        for (int jt = 0; jt < 8; ++jt) {
            f32x4 acc = {c2r[jt], c2r[jt], c2r[jt], c2r[jt]};
            #pragma unroll
            for (int kt = 0; kt < 4; ++kt)
                acc = __builtin_amdgcn_mfma_f32_16x16x32_bf16(
                    af[kt], ldsF[2048 + ((jt * 4 + kt) * 4 + q) * 16 + c], acc, 0, 0, 0);
            #pragma unroll
            for (int r = 0; r < 4; ++r) {
                float h = fast_tanh(acc[r]);
                px[r] = fmaf(h, v3r[jt].x, px[r]);
                py[r] = fmaf(h, v3r[jt].y, py[r]);
            }
        }

        // ===== post MLP: relu, W-weights (LDS slot 0) =====
        #pragma unroll
        for (int kt = 0; kt < 4; ++kt) {
            const float4* t4 = (const float4*)(tembW + i * HD + kt * 32 + q * 8);
            float4 ta = t4[0], tb = t4[1];
            float tv8[8] = {ta.x,ta.y,ta.z,ta.w,tb.x,tb.y,tb.z,tb.w};
            bf16x8 t;
            #pragma unroll
            for (int jj = 0; jj < 8; ++jj) {
                unsigned pp = projP[kt*4 + (jj >> 1)];
                float pv = (jj & 1) ? bfhi(pp) : bflo(pp);
                unsigned wz = wzP[kt*8+jj];
                float v = pv + tv8[jj] + zx * bflo(wz) + zy * bfhi(wz);
                t[jj] = f2bf(fmaxf(v, 0.0f));
            }
            af[kt] = t;
        }
        #pragma unroll
        for (int jt = 0; jt < 8; ++jt) {
            f32x4 acc = {b2r[jt], b2r[jt], b2r[jt], b2r[jt]};
            #pragma unroll
            for (int kt = 0; kt < 4; ++kt)
                acc = __builtin_amdgcn_mfma_f32_16x16x32_bf16(
                    af[kt], ldsF[((jt * 4 + kt) * 4 + q) * 16 + c], acc, 0, 0, 0);
            #pragma unroll
            for (int r = 0; r < 4; ++r) {
                float h = fmaxf(acc[r], 0.0f);
                px[r] = fmaf(h, w3r[jt].x, px[r]);
                py[r] = fmaf(h, w3r[jt].y, py[r]);
            }
        }

        // ===== reduce over the 16-lane column groups =====
        #pragma unroll
        for (int off = 1; off < 16; off <<= 1)
            #pragma unroll
            for (int r = 0; r < 4; ++r) {
                px[r] += __shfl_xor(px[r], off);
                py[r] += __shfl_xor(py[r], off);
            }

        // ===== z update (writer lanes c<4 own row q*4+c) =====
        int cc = c & 3;
        float sdx = px[0], sdy = py[0];
        sdx = (cc == 1) ? px[1] : sdx; sdy = (cc == 1) ? py[1] : sdy;
        sdx = (cc == 2) ? px[2] : sdx; sdy = (cc == 2) ? py[2] : sdy;
        sdx = (cc == 3) ? px[3] : sdx; sdy = (cc == 3) ? py[3] : sdy;
        float zox = __shfl(zx, myrow), zoy = __shfl(zy, myrow);
        float2 xiv = make_float2(0.0f, 0.0f);
        if (c < 4) xiv = xi2[(size_t)i * NP + m0 + myrow];
        float znx = fmaf(sdx, dt, zox) + xiv.x * ns;
        float zny = fmaf(sdy, dt, zoy) + xiv.y * ns;
        if (c < 4) out2[(size_t)(i + 1) * NP + m0 + myrow] = make_float2(znx, zny);
        int src = ((c >> 2) << 4) | (c & 3);
        zx = __shfl(znx, src);
        zy = __shfl(zny, src);
    }
}

extern "C" void kernel_launch(void* const* d_in, const int* in_sizes, int n_in,
                              void* d_out, int out_size, void* d_ws, size_t ws_size,
                              hipStream_t stream)
{
    const float* z0    = (const float*)d_in[0];
    const float* pctx  = (const float*)d_in[1];
    const float* cctx  = (const float*)d_in[2];
    const float* times = (const float*)d_in[3];
    const float* xi    = (const float*)d_in[4];
    const float* freqs = (const float*)d_in[5];
    const float* logd  = (const float*)d_in[6];
    const float* W1 = (const float*)d_in[7];
    const float* b1 = (const float*)d_in[8];
    const float* W2 = (const float*)d_in[9];
    const float* b2 = (const float*)d_in[10];
    const float* W3 = (const float*)d_in[11];
    const float* b3 = (const float*)d_in[12];
    const float* V1 = (const float*)d_in[13];
    const float* c1 = (const float*)d_in[14];
    const float* V2 = (const float*)d_in[15];
    const float* c2 = (const float*)d_in[16];
    const float* V3 = (const float*)d_in[17];
    const float* c3 = (const float*)d_in[18];

    short* packedW = (short*)d_ws;                       // 4 x 16384 shorts = 128 KB
    float* tembW = (float*)((char*)d_ws + 131072);       // [50][128]
    float* tV    = tembW + TSTEPS * HD;                  // [50][128]
    float* dtv   = tV + TSTEPS * HD;
    float* nsv   = dtv + 64;

    prep_kernel<<<1, 128, 0, stream>>>(times, freqs, logd, W1, b1, V1, c1,
                                       tembW, tV, dtv, nsv);
    pack_kernel<<<256, 256, 0, stream>>>(W1, V1, W2, V2, packedW);
    sde_kernel<<<NP / 64, 256, 0, stream>>>(z0, pctx, cctx, xi, packedW,
                                            W1, V1, b2, c2, W3, b3, V3, c3,
                                            tembW, tV, dtv, nsv,
                                            (float*)d_out);
}

// Round 3
// 5473.689 us; speedup vs baseline: 1.8821x; 1.1024x over previous
//
#include <hip/hip_runtime.h>
#include <math.h>

#define NP 65536
#define HD 128
#define TSTEPS 50

typedef short bf16x8 __attribute__((ext_vector_type(8)));
typedef float f32x4 __attribute__((ext_vector_type(4)));

__device__ __forceinline__ short f2bf(float f) {
    union { float f; unsigned u; } v; v.f = f;
    unsigned r = v.u + 0x7fffu + ((v.u >> 16) & 1u);
    return (short)(r >> 16);
}
__device__ __forceinline__ unsigned packbf(float a, float b) {
    return ((unsigned)(unsigned short)f2bf(a)) | (((unsigned)(unsigned short)f2bf(b)) << 16);
}
__device__ __forceinline__ float bflo(unsigned u){ union{unsigned u; float f;} v; v.u = u << 16; return v.f; }
__device__ __forceinline__ float bfhi(unsigned u){ union{unsigned u; float f;} v; v.u = u & 0xffff0000u; return v.f; }

__device__ __forceinline__ float fast_tanh(float x) {
    float e = __builtin_amdgcn_exp2f(x * 2.8853900817779268f);
    return 1.0f - 2.0f * __builtin_amdgcn_rcpf(e + 1.0f);
}

// ---------------------------------------------------------------------------
// Per-step tables; one block per step i.
// ---------------------------------------------------------------------------
__global__ __launch_bounds__(128) void prep_kernel(
    const float* __restrict__ times, const float* __restrict__ freqs,
    const float* __restrict__ log_diff,
    const float* __restrict__ W1, const float* __restrict__ b1,
    const float* __restrict__ V1, const float* __restrict__ c1,
    float* __restrict__ tembW, float* __restrict__ tV,
    float* __restrict__ dtv, float* __restrict__ nsv)
{
    int j = threadIdx.x;
    int i = blockIdx.x;
    float ld = log_diff[0];
    float gb = (ld > 20.0f) ? ld : log1pf(expf(ld));  // softplus
    float t  = times[i];
    float dt = times[i + 1] - t;
    float acc = b1[j];
    #pragma unroll
    for (int m = 0; m < 16; ++m) {
        float a = 6.283185307179586f * t * freqs[m];
        float sn, cs;
        sincosf(a, &sn, &cs);
        acc = fmaf(sn, W1[(130 + m) * HD + j], acc);
        acc = fmaf(cs, W1[(146 + m) * HD + j], acc);
    }
    tembW[i * HD + j] = acc;
    tV[i * HD + j] = fmaf(t, V1[130 * HD + j], c1[j]);
    if (j == 0) {
        dtv[i] = dt;
        nsv[i] = gb * (1.0f - t) * sqrtf(fmaxf(dt, 1e-12f));
    }
}

// ---------------------------------------------------------------------------
// Pack 4 weight matrices (W1ctx, V1ctx, W2, V2) into bf16 B-fragment order:
// frag idx = ((jt*4+kt)*4+q)*16+c, element j;  k = kt*32+q*8+j, n = jt*16+c.
// ---------------------------------------------------------------------------
__global__ __launch_bounds__(256) void pack_kernel(
    const float* __restrict__ W1, const float* __restrict__ V1,
    const float* __restrict__ W2, const float* __restrict__ V2,
    short* __restrict__ packed)
{
    int gi = blockIdx.x * 256 + threadIdx.x;   // 0..65535
    int mat = gi >> 14;
    int s = gi & 16383;
    int j  = s & 7;
    int cc = (s >> 3) & 15;
    int qq = (s >> 7) & 3;
    int kt = (s >> 9) & 3;
    int jt = (s >> 11) & 7;
    int k = kt * 32 + qq * 8 + j;
    int n = jt * 16 + cc;
    float v;
    if      (mat == 0) v = W1[(2 + k) * HD + n];
    else if (mat == 1) v = V1[(2 + k) * HD + n];
    else if (mat == 2) v = W2[k * HD + n];
    else               v = V2[k * HD + n];
    packed[gi] = f2bf(v);
}

// ---------------------------------------------------------------------------
// Persistent SDE kernel: wave owns 16 particles (M=16 MFMA row tile) for all
// 50 steps.  Lane computes H1 directly in A-operand layout (m=lane&15,
// k=quad*8+j) -> no transform between layer1 and layer2 MFMA.
// All wave-shared in-loop constants live in LDS (NOT registers -> no scratch
// spills, which were 10.4 GB of HBM traffic in round 2).
// ---------------------------------------------------------------------------
__global__ __launch_bounds__(256, 2) void sde_kernel(
    const float* __restrict__ z0, const float* __restrict__ pctx,
    const float* __restrict__ cctx, const float* __restrict__ xi,
    const short* __restrict__ packedW,
    const float* __restrict__ W1, const float* __restrict__ V1,
    const float* __restrict__ b2, const float* __restrict__ c2,
    const float* __restrict__ W3, const float* __restrict__ b3,
    const float* __restrict__ V3, const float* __restrict__ c3,
    const float* __restrict__ tembW, const float* __restrict__ tV,
    const float* __restrict__ dtv, const float* __restrict__ nsv,
    float* __restrict__ out)
{
    __shared__ char smem[71680];            // 66 KB frag/staging + 4 KB tables
    float* stg = (float*)smem;
    const bf16x8* ldsF = (const bf16x8*)smem;
    unsigned* zwPs = (unsigned*)(smem + 67584);   // packed (W1[0][k],W1[1][k])
    unsigned* zwCs = (unsigned*)(smem + 68096);
    float*    b2s  = (float*)(smem + 68608);
    float*    c2s  = (float*)(smem + 69120);
    float2*   w3s  = (float2*)(smem + 69632);
    float2*   v3s  = (float2*)(smem + 70656);

    int tid = threadIdx.x;
    int lane = tid & 63, wv = tid >> 6;
    int q = lane >> 4, c = lane & 15;
    int m0 = blockIdx.x * 64 + wv * 16;     // wave's 16-row base
    int mrow = m0 + c;                      // this lane's A-layout row

    // ---- small constant tables -> LDS (covered by the phase-1 barrier) ----
    if (tid < 128) {
        zwPs[tid] = packbf(W1[tid], W1[HD + tid]);
        zwCs[tid] = packbf(V1[tid], V1[HD + tid]);
        b2s[tid] = b2[tid];
        c2s[tid] = c2[tid];
        w3s[tid] = ((const float2*)W3)[tid];
        v3s[tid] = ((const float2*)V3)[tid];
    }

    // ---- phase 1: W1ctx/V1ctx fragments -> LDS (coalesced copy) ----
    {
        const uint4* src = (const uint4*)packedW;   // mats 0,1 = 64 KB
        uint4* dst = (uint4*)smem;
        #pragma unroll
        for (int i = 0; i < 16; ++i) dst[i * 256 + tid] = src[i * 256 + tid];
    }
    __syncthreads();

    // ---- ctx A-fragments ----
    bf16x8 pf[4], cf[4];
    #pragma unroll
    for (int kt = 0; kt < 4; ++kt) {
        const float4* p4 = (const float4*)(pctx + (size_t)mrow * HD + kt * 32 + q * 8);
        float4 a = p4[0], b = p4[1];
        bf16x8 t;
        t[0]=f2bf(a.x); t[1]=f2bf(a.y); t[2]=f2bf(a.z); t[3]=f2bf(a.w);
        t[4]=f2bf(b.x); t[5]=f2bf(b.y); t[6]=f2bf(b.z); t[7]=f2bf(b.w);
        pf[kt] = t;
        const float4* c4 = (const float4*)(cctx + (size_t)mrow * HD + kt * 32 + q * 8);
        float4 e = c4[0], d = c4[1];
        bf16x8 u;
        u[0]=f2bf(e.x); u[1]=f2bf(e.y); u[2]=f2bf(e.z); u[3]=f2bf(e.w);
        u[4]=f2bf(d.x); u[5]=f2bf(d.y); u[6]=f2bf(d.z); u[7]=f2bf(d.w);
        cf[kt] = u;
    }

    // ---- ctx projection MFMAs (step-invariant) ----
    f32x4 accP[8], accC[8];
    #pragma unroll
    for (int jt = 0; jt < 8; ++jt) {
        f32x4 ap = {0.f,0.f,0.f,0.f}, ac = {0.f,0.f,0.f,0.f};
        #pragma unroll
        for (int kt = 0; kt < 4; ++kt) {
            int fi = ((jt * 4 + kt) * 4 + q) * 16 + c;
            ap = __builtin_amdgcn_mfma_f32_16x16x32_bf16(pf[kt], ldsF[fi], ap, 0, 0, 0);
            ac = __builtin_amdgcn_mfma_f32_16x16x32_bf16(cf[kt], ldsF[2048 + fi], ac, 0, 0, 0);
        }
        accP[jt] = ap; accC[jt] = ac;
    }
    __syncthreads();

    // ---- C-layout -> A-layout round trip through LDS (once) ----
    #pragma unroll
    for (int jt = 0; jt < 8; ++jt)
        #pragma unroll
        for (int r = 0; r < 4; ++r) {
            stg[(wv * 16 + q * 4 + r) * 132 + jt * 16 + c]        = accP[jt][r];
            stg[8448 + (wv * 16 + q * 4 + r) * 132 + jt * 16 + c] = accC[jt][r];
        }
    __syncthreads();
    unsigned projP[16], projC[16];
    #pragma unroll
    for (int kt = 0; kt < 4; ++kt) {
        const float4* rp = (const float4*)(stg + (wv * 16 + c) * 132 + kt * 32 + q * 8);
        float4 a = rp[0], b = rp[1];
        projP[kt*4+0] = packbf(a.x, a.y); projP[kt*4+1] = packbf(a.z, a.w);
        projP[kt*4+2] = packbf(b.x, b.y); projP[kt*4+3] = packbf(b.z, b.w);
        const float4* rc = (const float4*)(stg + 8448 + (wv * 16 + c) * 132 + kt * 32 + q * 8);
        float4 e = rc[0], d = rc[1];
        projC[kt*4+0] = packbf(e.x, e.y); projC[kt*4+1] = packbf(e.z, e.w);
        projC[kt*4+2] = packbf(d.x, d.y); projC[kt*4+3] = packbf(d.z, d.w);
    }
    __syncthreads();

    // ---- phase 3: W2/V2 fragments -> LDS (resident for all 50 steps) ----
    {
        const uint4* src = (const uint4*)(packedW + 32768);  // mats 2,3
        uint4* dst = (uint4*)smem;
        #pragma unroll
        for (int i = 0; i < 16; ++i) dst[i * 256 + tid] = src[i * 256 + tid];
    }
    __syncthreads();

    float b3x = b3[0] + c3[0], b3y = b3[1] + c3[1];

    const float2* z02 = (const float2*)z0;
    const float2* xi2 = (const float2*)xi;
    float2* out2 = (float2*)out;

    float2 zi = z02[mrow];
    float zx = zi.x, zy = zi.y;          // z for row m = c (A-layout row)
    int myrow = q * 4 + (c & 3);         // row this lane writes (if c<4)
    {
        float t0x = __shfl(zx, myrow), t0y = __shfl(zy, myrow);
        if (c < 4) out2[m0 + myrow] = make_float2(t0x, t0y);
    }

    for (int i = 0; i < TSTEPS; ++i) {
        float dt = dtv[i], ns = nsv[i];
        float px[4], py[4];
        #pragma unroll
        for (int r = 0; r < 4; ++r) { px[r] = b3x; py[r] = b3y; }

        // ===== cnf MLP: tanh, V-weights (LDS slot 1) =====
        bf16x8 af[4];
        #pragma unroll
        for (int kt = 0; kt < 4; ++kt) {
            const float4* t4 = (const float4*)(tV + i * HD + kt * 32 + q * 8);
            float4 ta = t4[0], tb = t4[1];
            float tv8[8] = {ta.x,ta.y,ta.z,ta.w,tb.x,tb.y,tb.z,tb.w};
            const uint4* zw4 = (const uint4*)(zwCs + kt * 32 + q * 8);
            uint4 zwa = zw4[0], zwb = zw4[1];
            unsigned zw8[8] = {zwa.x,zwa.y,zwa.z,zwa.w,zwb.x,zwb.y,zwb.z,zwb.w};
            bf16x8 t;
            #pragma unroll
            for (int jj = 0; jj < 8; ++jj) {
                unsigned pp = projC[kt*4 + (jj >> 1)];
                float pv = (jj & 1) ? bfhi(pp) : bflo(pp);
                unsigned wz = zw8[jj];
                float v = pv + tv8[jj] + zx * bflo(wz) + zy * bfhi(wz);
                t[jj] = f2bf(fast_tanh(v));
            }
            af[kt] = t;
        }
        #pragma unroll
        for (int jt = 0; jt < 8; ++jt) {
            float cb = c2s[jt * 16 + c];
            f32x4 acc = {cb, cb, cb, cb};
            #pragma unroll
            for (int kt = 0; kt < 4; ++kt)
                acc = __builtin_amdgcn_mfma_f32_16x16x32_bf16(
                    af[kt], ldsF[2048 + ((jt * 4 + kt) * 4 + q) * 16 + c], acc, 0, 0, 0);
            float2 v3 = v3s[jt * 16 + c];
            #pragma unroll
            for (int r = 0; r < 4; ++r) {
                float h = fast_tanh(acc[r]);
                px[r] = fmaf(h, v3.x, px[r]);
                py[r] = fmaf(h, v3.y, py[r]);
            }
        }

        // ===== post MLP: relu, W-weights (LDS slot 0) =====
        #pragma unroll
        for (int kt = 0; kt < 4; ++kt) {
            const float4* t4 = (const float4*)(tembW + i * HD + kt * 32 + q * 8);
            float4 ta = t4[0], tb = t4[1];
            float tv8[8] = {ta.x,ta.y,ta.z,ta.w,tb.x,tb.y,tb.z,tb.w};
            const uint4* zw4 = (const uint4*)(zwPs + kt * 32 + q * 8);
            uint4 zwa = zw4[0], zwb = zw4[1];
            unsigned zw8[8] = {zwa.x,zwa.y,zwa.z,zwa.w,zwb.x,zwb.y,zwb.z,zwb.w};
            bf16x8 t;
            #pragma unroll
            for (int jj = 0; jj < 8; ++jj) {
                unsigned pp = projP[kt*4 + (jj >> 1)];
                float pv = (jj & 1) ? bfhi(pp) : bflo(pp);
                unsigned wz = zw8[jj];
                float v = pv + tv8[jj] + zx * bflo(wz) + zy * bfhi(wz);
                t[jj] = f2bf(fmaxf(v, 0.0f));
            }
            af[kt] = t;
        }
        #pragma unroll
        for (int jt = 0; jt < 8; ++jt) {
            float bb = b2s[jt * 16 + c];
            f32x4 acc = {bb, bb, bb, bb};
            #pragma unroll
            for (int kt = 0; kt < 4; ++kt)
                acc = __builtin_amdgcn_mfma_f32_16x16x32_bf16(
                    af[kt], ldsF[((jt * 4 + kt) * 4 + q) * 16 + c], acc, 0, 0, 0);
            float2 w3 = w3s[jt * 16 + c];
            #pragma unroll
            for (int r = 0; r < 4; ++r) {
                float h = fmaxf(acc[r], 0.0f);
                px[r] = fmaf(h, w3.x, px[r]);
                py[r] = fmaf(h, w3.y, py[r]);
            }
        }

        // ===== reduce over the 16-lane column groups =====
        #pragma unroll
        for (int off = 1; off < 16; off <<= 1)
            #pragma unroll
            for (int r = 0; r < 4; ++r) {
                px[r] += __shfl_xor(px[r], off);
                py[r] += __shfl_xor(py[r], off);
            }

        // ===== z update (writer lanes c<4 own row q*4+c) =====
        int cc = c & 3;
        float sdx = px[0], sdy = py[0];
        sdx = (cc == 1) ? px[1] : sdx; sdy = (cc == 1) ? py[1] : sdy;
        sdx = (cc == 2) ? px[2] : sdx; sdy = (cc == 2) ? py[2] : sdy;
        sdx = (cc == 3) ? px[3] : sdx; sdy = (cc == 3) ? py[3] : sdy;
        float zox = __shfl(zx, myrow), zoy = __shfl(zy, myrow);
        float2 xiv = make_float2(0.0f, 0.0f);
        if (c < 4) xiv = xi2[(size_t)i * NP + m0 + myrow];
        float znx = fmaf(sdx, dt, zox) + xiv.x * ns;
        float zny = fmaf(sdy, dt, zoy) + xiv.y * ns;
        if (c < 4) out2[(size_t)(i + 1) * NP + m0 + myrow] = make_float2(znx, zny);
        int src = ((c >> 2) << 4) | (c & 3);
        zx = __shfl(znx, src);
        zy = __shfl(zny, src);
    }
}

extern "C" void kernel_launch(void* const* d_in, const int* in_sizes, int n_in,
                              void* d_out, int out_size, void* d_ws, size_t ws_size,
                              hipStream_t stream)
{
    const float* z0    = (const float*)d_in[0];
    const float* pctx  = (const float*)d_in[1];
    const float* cctx  = (const float*)d_in[2];
    const float* times = (const float*)d_in[3];
    const float* xi    = (const float*)d_in[4];
    const float* freqs = (const float*)d_in[5];
    const float* logd  = (const float*)d_in[6];
    const float* W1 = (const float*)d_in[7];
    const float* b1 = (const float*)d_in[8];
    const float* W2 = (const float*)d_in[9];
    const float* b2 = (const float*)d_in[10];
    const float* W3 = (const float*)d_in[11];
    const float* b3 = (const float*)d_in[12];
    const float* V1 = (const float*)d_in[13];
    const float* c1 = (const float*)d_in[14];
    const float* V2 = (const float*)d_in[15];
    const float* c2 = (const float*)d_in[16];
    const float* V3 = (const float*)d_in[17];
    const float* c3 = (const float*)d_in[18];

    short* packedW = (short*)d_ws;                       // 4 x 16384 shorts = 128 KB
    float* tembW = (float*)((char*)d_ws + 131072);       // [50][128]
    float* tV    = tembW + TSTEPS * HD;                  // [50][128]
    float* dtv   = tV + TSTEPS * HD;
    float* nsv   = dtv + 64;

    prep_kernel<<<TSTEPS, 128, 0, stream>>>(times, freqs, logd, W1, b1, V1, c1,
                                            tembW, tV, dtv, nsv);
    pack_kernel<<<256, 256, 0, stream>>>(W1, V1, W2, V2, packedW);
    sde_kernel<<<NP / 64, 256, 0, stream>>>(z0, pctx, cctx, xi, packedW,
                                            W1, V1, b2, c2, W3, b3, V3, c3,
                                            tembW, tV, dtv, nsv,
                                            (float*)d_out);
}

// Round 4
// 710.801 us; speedup vs baseline: 14.4936x; 7.7007x over previous
//
#include <hip/hip_runtime.h>
#include <math.h>

#define NP 65536
#define HD 128
#define TSTEPS 50

typedef short bf16x8 __attribute__((ext_vector_type(8)));
typedef float f32x4 __attribute__((ext_vector_type(4)));

__device__ __forceinline__ short f2bf(float f) {
    union { float f; unsigned u; } v; v.f = f;
    unsigned r = v.u + 0x7fffu + ((v.u >> 16) & 1u);
    return (short)(r >> 16);
}
__device__ __forceinline__ unsigned packbf(float a, float b) {
    return ((unsigned)(unsigned short)f2bf(a)) | (((unsigned)(unsigned short)f2bf(b)) << 16);
}
__device__ __forceinline__ float bflo(unsigned u){ union{unsigned u; float f;} v; v.u = u << 16; return v.f; }
__device__ __forceinline__ float bfhi(unsigned u){ union{unsigned u; float f;} v; v.u = u & 0xffff0000u; return v.f; }

__device__ __forceinline__ float fast_tanh(float x) {
    float e = __builtin_amdgcn_exp2f(x * 2.8853900817779268f);
    return 1.0f - 2.0f * __builtin_amdgcn_rcpf(e + 1.0f);
}

// ---------------------------------------------------------------------------
// Per-step tables; one block per step i.
// ---------------------------------------------------------------------------
__global__ __launch_bounds__(128) void prep_kernel(
    const float* __restrict__ times, const float* __restrict__ freqs,
    const float* __restrict__ log_diff,
    const float* __restrict__ W1, const float* __restrict__ b1,
    const float* __restrict__ V1, const float* __restrict__ c1,
    float* __restrict__ tembW, float* __restrict__ tV,
    float* __restrict__ dtv, float* __restrict__ nsv)
{
    int j = threadIdx.x;
    int i = blockIdx.x;
    float ld = log_diff[0];
    float gb = (ld > 20.0f) ? ld : log1pf(expf(ld));  // softplus
    float t  = times[i];
    float dt = times[i + 1] - t;
    float acc = b1[j];
    #pragma unroll
    for (int m = 0; m < 16; ++m) {
        float a = 6.283185307179586f * t * freqs[m];
        float sn, cs;
        sincosf(a, &sn, &cs);
        acc = fmaf(sn, W1[(130 + m) * HD + j], acc);
        acc = fmaf(cs, W1[(146 + m) * HD + j], acc);
    }
    tembW[i * HD + j] = acc;
    tV[i * HD + j] = fmaf(t, V1[130 * HD + j], c1[j]);
    if (j == 0) {
        dtv[i] = dt;
        nsv[i] = gb * (1.0f - t) * sqrtf(fmaxf(dt, 1e-12f));
    }
}

// ---------------------------------------------------------------------------
// Pack 4 weight matrices (W1ctx, V1ctx, W2, V2) into bf16 B-fragment order:
// frag idx = ((jt*4+kt)*4+q)*16+c, element j;  k = kt*32+q*8+j, n = jt*16+c.
// ---------------------------------------------------------------------------
__global__ __launch_bounds__(256) void pack_kernel(
    const float* __restrict__ W1, const float* __restrict__ V1,
    const float* __restrict__ W2, const float* __restrict__ V2,
    short* __restrict__ packed)
{
    int gi = blockIdx.x * 256 + threadIdx.x;   // 0..65535
    int mat = gi >> 14;
    int s = gi & 16383;
    int j  = s & 7;
    int cc = (s >> 3) & 15;
    int qq = (s >> 7) & 3;
    int kt = (s >> 9) & 3;
    int jt = (s >> 11) & 7;
    int k = kt * 32 + qq * 8 + j;
    int n = jt * 16 + cc;
    float v;
    if      (mat == 0) v = W1[(2 + k) * HD + n];
    else if (mat == 1) v = V1[(2 + k) * HD + n];
    else if (mat == 2) v = W2[k * HD + n];
    else               v = V2[k * HD + n];
    packed[gi] = f2bf(v);
}

// ---------------------------------------------------------------------------
// Persistent SDE kernel: wave owns 16 particles (M=16 MFMA row tile) for all
// 50 steps.  Lane computes H1 directly in A-operand layout (m=lane&15,
// k=quad*8+j) -> no transform between layer1 and layer2 MFMA.
// R4: per-step tV/tembW staged per-wave into LDS (double-buffered, prefetch
// a full step ahead) -> no per-step per-lane global table reads; output
// stores coalesced via shfl to 16 consecutive lanes; xi loaded by all lanes.
// ---------------------------------------------------------------------------
__global__ __launch_bounds__(256, 2) void sde_kernel(
    const float* __restrict__ z0, const float* __restrict__ pctx,
    const float* __restrict__ cctx, const float* __restrict__ xi,
    const short* __restrict__ packedW,
    const float* __restrict__ W1, const float* __restrict__ V1,
    const float* __restrict__ b2, const float* __restrict__ c2,
    const float* __restrict__ W3, const float* __restrict__ b3,
    const float* __restrict__ V3, const float* __restrict__ c3,
    const float* __restrict__ tembW, const float* __restrict__ tV,
    const float* __restrict__ dtv, const float* __restrict__ nsv,
    float* __restrict__ out)
{
    __shared__ char smem[79872];            // 66K frag/stg + 4K tables + 8K tslots
    float* stg = (float*)smem;
    const bf16x8* ldsF = (const bf16x8*)smem;
    unsigned* zwPs = (unsigned*)(smem + 67584);   // packed (W1[0][k],W1[1][k])
    unsigned* zwCs = (unsigned*)(smem + 68096);
    float*    b2s  = (float*)(smem + 68608);
    float*    c2s  = (float*)(smem + 69120);
    float2*   w3s  = (float2*)(smem + 69632);
    float2*   v3s  = (float2*)(smem + 70656);

    int tid = threadIdx.x;
    int lane = tid & 63, wv = tid >> 6;
    int q = lane >> 4, c = lane & 15;
    int m0 = blockIdx.x * 64 + wv * 16;     // wave's 16-row base
    int mrow = m0 + c;                      // this lane's A-layout row

    // per-wave table slot: 2 buffers x 256 floats (tV[0:128] ++ tembW[128:256])
    float* tslot = (float*)(smem + 71680) + wv * 512;

    // ---- small constant tables -> LDS (covered by the phase-1 barrier) ----
    if (tid < 128) {
        zwPs[tid] = packbf(W1[tid], W1[HD + tid]);
        zwCs[tid] = packbf(V1[tid], V1[HD + tid]);
        b2s[tid] = b2[tid];
        c2s[tid] = c2[tid];
        w3s[tid] = ((const float2*)W3)[tid];
        v3s[tid] = ((const float2*)V3)[tid];
    }

    // ---- phase 1: W1ctx/V1ctx fragments -> LDS (coalesced copy) ----
    {
        const uint4* src = (const uint4*)packedW;   // mats 0,1 = 64 KB
        uint4* dst = (uint4*)smem;
        #pragma unroll
        for (int i = 0; i < 16; ++i) dst[i * 256 + tid] = src[i * 256 + tid];
    }
    __syncthreads();

    // ---- ctx A-fragments ----
    bf16x8 pf[4], cf[4];
    #pragma unroll
    for (int kt = 0; kt < 4; ++kt) {
        const float4* p4 = (const float4*)(pctx + (size_t)mrow * HD + kt * 32 + q * 8);
        float4 a = p4[0], b = p4[1];
        bf16x8 t;
        t[0]=f2bf(a.x); t[1]=f2bf(a.y); t[2]=f2bf(a.z); t[3]=f2bf(a.w);
        t[4]=f2bf(b.x); t[5]=f2bf(b.y); t[6]=f2bf(b.z); t[7]=f2bf(b.w);
        pf[kt] = t;
        const float4* c4 = (const float4*)(cctx + (size_t)mrow * HD + kt * 32 + q * 8);
        float4 e = c4[0], d = c4[1];
        bf16x8 u;
        u[0]=f2bf(e.x); u[1]=f2bf(e.y); u[2]=f2bf(e.z); u[3]=f2bf(e.w);
        u[4]=f2bf(d.x); u[5]=f2bf(d.y); u[6]=f2bf(d.z); u[7]=f2bf(d.w);
        cf[kt] = u;
    }

    // ---- ctx projection MFMAs (step-invariant) ----
    f32x4 accP[8], accC[8];
    #pragma unroll
    for (int jt = 0; jt < 8; ++jt) {
        f32x4 ap = {0.f,0.f,0.f,0.f}, ac = {0.f,0.f,0.f,0.f};
        #pragma unroll
        for (int kt = 0; kt < 4; ++kt) {
            int fi = ((jt * 4 + kt) * 4 + q) * 16 + c;
            ap = __builtin_amdgcn_mfma_f32_16x16x32_bf16(pf[kt], ldsF[fi], ap, 0, 0, 0);
            ac = __builtin_amdgcn_mfma_f32_16x16x32_bf16(cf[kt], ldsF[2048 + fi], ac, 0, 0, 0);
        }
        accP[jt] = ap; accC[jt] = ac;
    }
    __syncthreads();

    // ---- C-layout -> A-layout round trip through LDS (once) ----
    #pragma unroll
    for (int jt = 0; jt < 8; ++jt)
        #pragma unroll
        for (int r = 0; r < 4; ++r) {
            stg[(wv * 16 + q * 4 + r) * 132 + jt * 16 + c]        = accP[jt][r];
            stg[8448 + (wv * 16 + q * 4 + r) * 132 + jt * 16 + c] = accC[jt][r];
        }
    __syncthreads();
    unsigned projP[16], projC[16];
    #pragma unroll
    for (int kt = 0; kt < 4; ++kt) {
        const float4* rp = (const float4*)(stg + (wv * 16 + c) * 132 + kt * 32 + q * 8);
        float4 a = rp[0], b = rp[1];
        projP[kt*4+0] = packbf(a.x, a.y); projP[kt*4+1] = packbf(a.z, a.w);
        projP[kt*4+2] = packbf(b.x, b.y); projP[kt*4+3] = packbf(b.z, b.w);
        const float4* rc = (const float4*)(stg + 8448 + (wv * 16 + c) * 132 + kt * 32 + q * 8);
        float4 e = rc[0], d = rc[1];
        projC[kt*4+0] = packbf(e.x, e.y); projC[kt*4+1] = packbf(e.z, e.w);
        projC[kt*4+2] = packbf(d.x, d.y); projC[kt*4+3] = packbf(d.z, d.w);
    }
    __syncthreads();

    // ---- phase 3: W2/V2 fragments -> LDS (resident for all 50 steps) ----
    {
        const uint4* src = (const uint4*)(packedW + 32768);  // mats 2,3
        uint4* dst = (uint4*)smem;
        #pragma unroll
        for (int i = 0; i < 16; ++i) dst[i * 256 + tid] = src[i * 256 + tid];
    }
    __syncthreads();

    float b3x = b3[0] + c3[0], b3y = b3[1] + c3[1];

    const float2* z02 = (const float2*)z0;
    const float2* xi2 = (const float2*)xi;
    float2* out2 = (float2*)out;

    // ---- stage step-0 tables into buf 0 (wave-private, no barrier) ----
    {
        const float4* srcp = (lane < 32)
            ? ((const float4*)(tV) + lane)
            : ((const float4*)(tembW) + (lane - 32));
        *((float4*)tslot + lane) = *srcp;
    }

    float2 zi = z02[mrow];
    float zx = zi.x, zy = zi.y;          // z for row m = c (A-layout row)
    int row_mine = q * 4 + (c & 3);      // row whose update this lane computes
    if (lane < 16) out2[m0 + lane] = make_float2(zx, zy);   // lane l holds row l

    for (int i = 0; i < TSTEPS; ++i) {
        int b = i & 1;
        const float* tb = tslot + b * 256;

        // prefetch next step's table slice (consumed at end of step)
        int sN = (i + 1 < TSTEPS) ? i + 1 : i;
        float4 pfv;
        {
            const float4* srcp = (lane < 32)
                ? ((const float4*)(tV + sN * HD) + lane)
                : ((const float4*)(tembW + sN * HD) + (lane - 32));
            pfv = *srcp;
        }
        // xi + step scalars, hoisted
        float dt = dtv[i], ns = nsv[i];
        float2 xiv = xi2[(size_t)i * NP + m0 + row_mine];

        float px[4], py[4];
        #pragma unroll
        for (int r = 0; r < 4; ++r) { px[r] = b3x; py[r] = b3y; }

        // ===== cnf MLP: tanh, V-weights (LDS slot 1) =====
        bf16x8 af[4];
        #pragma unroll
        for (int kt = 0; kt < 4; ++kt) {
            const float4* t4 = (const float4*)(tb + kt * 32 + q * 8);
            float4 ta = t4[0], tbv = t4[1];
            float tv8[8] = {ta.x,ta.y,ta.z,ta.w,tbv.x,tbv.y,tbv.z,tbv.w};
            const uint4* zw4 = (const uint4*)(zwCs + kt * 32 + q * 8);
            uint4 zwa = zw4[0], zwb = zw4[1];
            unsigned zw8[8] = {zwa.x,zwa.y,zwa.z,zwa.w,zwb.x,zwb.y,zwb.z,zwb.w};
            bf16x8 t;
            #pragma unroll
            for (int jj = 0; jj < 8; ++jj) {
                unsigned pp = projC[kt*4 + (jj >> 1)];
                float pv = (jj & 1) ? bfhi(pp) : bflo(pp);
                unsigned wz = zw8[jj];
                float v = pv + tv8[jj] + zx * bflo(wz) + zy * bfhi(wz);
                t[jj] = f2bf(fast_tanh(v));
            }
            af[kt] = t;
        }
        #pragma unroll
        for (int jt = 0; jt < 8; ++jt) {
            float cb = c2s[jt * 16 + c];
            f32x4 acc = {cb, cb, cb, cb};
            #pragma unroll
            for (int kt = 0; kt < 4; ++kt)
                acc = __builtin_amdgcn_mfma_f32_16x16x32_bf16(
                    af[kt], ldsF[2048 + ((jt * 4 + kt) * 4 + q) * 16 + c], acc, 0, 0, 0);
            float2 v3 = v3s[jt * 16 + c];
            #pragma unroll
            for (int r = 0; r < 4; ++r) {
                float h = fast_tanh(acc[r]);
                px[r] = fmaf(h, v3.x, px[r]);
                py[r] = fmaf(h, v3.y, py[r]);
            }
        }

        // ===== post MLP: relu, W-weights (LDS slot 0) =====
        #pragma unroll
        for (int kt = 0; kt < 4; ++kt) {
            const float4* t4 = (const float4*)(tb + 128 + kt * 32 + q * 8);
            float4 ta = t4[0], tbv = t4[1];
            float tv8[8] = {ta.x,ta.y,ta.z,ta.w,tbv.x,tbv.y,tbv.z,tbv.w};
            const uint4* zw4 = (const uint4*)(zwPs + kt * 32 + q * 8);
            uint4 zwa = zw4[0], zwb = zw4[1];
            unsigned zw8[8] = {zwa.x,zwa.y,zwa.z,zwa.w,zwb.x,zwb.y,zwb.z,zwb.w};
            bf16x8 t;
            #pragma unroll
            for (int jj = 0; jj < 8; ++jj) {
                unsigned pp = projP[kt*4 + (jj >> 1)];
                float pv = (jj & 1) ? bfhi(pp) : bflo(pp);
                unsigned wz = zw8[jj];
                float v = pv + tv8[jj] + zx * bflo(wz) + zy * bfhi(wz);
                t[jj] = f2bf(fmaxf(v, 0.0f));
            }
            af[kt] = t;
        }
        #pragma unroll
        for (int jt = 0; jt < 8; ++jt) {
            float bb = b2s[jt * 16 + c];
            f32x4 acc = {bb, bb, bb, bb};
            #pragma unroll
            for (int kt = 0; kt < 4; ++kt)
                acc = __builtin_amdgcn_mfma_f32_16x16x32_bf16(
                    af[kt], ldsF[((jt * 4 + kt) * 4 + q) * 16 + c], acc, 0, 0, 0);
            float2 w3 = w3s[jt * 16 + c];
            #pragma unroll
            for (int r = 0; r < 4; ++r) {
                float h = fmaxf(acc[r], 0.0f);
                px[r] = fmaf(h, w3.x, px[r]);
                py[r] = fmaf(h, w3.y, py[r]);
            }
        }

        // write prefetched tables to the other buffer (global load had the
        // whole step to land; next iteration's ds_reads sync via lgkmcnt)
        *((float4*)(tslot + (b ^ 1) * 256) + lane) = pfv;

        // ===== reduce over the 16-lane column groups =====
        #pragma unroll
        for (int off = 1; off < 16; off <<= 1)
            #pragma unroll
            for (int r = 0; r < 4; ++r) {
                px[r] += __shfl_xor(px[r], off);
                py[r] += __shfl_xor(py[r], off);
            }

        // ===== z update: every lane computes its row_mine =====
        int cc = c & 3;
        float sdx = px[0], sdy = py[0];
        sdx = (cc == 1) ? px[1] : sdx; sdy = (cc == 1) ? py[1] : sdy;
        sdx = (cc == 2) ? px[2] : sdx; sdy = (cc == 2) ? py[2] : sdy;
        sdx = (cc == 3) ? px[3] : sdx; sdy = (cc == 3) ? py[3] : sdy;
        float zox = __shfl(zx, row_mine), zoy = __shfl(zy, row_mine);
        float znx = fmaf(sdx, dt, zox) + xiv.x * ns;
        float zny = fmaf(sdy, dt, zoy) + xiv.y * ns;

        // coalesced store: lanes 0..15 hold rows 0..15 after one shfl
        int src_store = ((lane >> 2) << 4) | (lane & 3);
        float sx = __shfl(znx, src_store);
        float sy = __shfl(zny, src_store);
        if (lane < 16) out2[(size_t)(i + 1) * NP + m0 + lane] = make_float2(sx, sy);

        // re-broadcast z for next step's A-layout (lane holds row c)
        int src_z = ((c >> 2) << 4) | (c & 3);
        zx = __shfl(znx, src_z);
        zy = __shfl(zny, src_z);
    }
}

extern "C" void kernel_launch(void* const* d_in, const int* in_sizes, int n_in,
                              void* d_out, int out_size, void* d_ws, size_t ws_size,
                              hipStream_t stream)
{
    const float* z0    = (const float*)d_in[0];
    const float* pctx  = (const float*)d_in[1];
    const float* cctx  = (const float*)d_in[2];
    const float* times = (const float*)d_in[3];
    const float* xi    = (const float*)d_in[4];
    const float* freqs = (const float*)d_in[5];
    const float* logd  = (const float*)d_in[6];
    const float* W1 = (const float*)d_in[7];
    const float* b1 = (const float*)d_in[8];
    const float* W2 = (const float*)d_in[9];
    const float* b2 = (const float*)d_in[10];
    const float* W3 = (const float*)d_in[11];
    const float* b3 = (const float*)d_in[12];
    const float* V1 = (const float*)d_in[13];
    const float* c1 = (const float*)d_in[14];
    const float* V2 = (const float*)d_in[15];
    const float* c2 = (const float*)d_in[16];
    const float* V3 = (const float*)d_in[17];
    const float* c3 = (const float*)d_in[18];

    short* packedW = (short*)d_ws;                       // 4 x 16384 shorts = 128 KB
    float* tembW = (float*)((char*)d_ws + 131072);       // [50][128]
    float* tV    = tembW + TSTEPS * HD;                  // [50][128]
    float* dtv   = tV + TSTEPS * HD;
    float* nsv   = dtv + 64;

    prep_kernel<<<TSTEPS, 128, 0, stream>>>(times, freqs, logd, W1, b1, V1, c1,
                                            tembW, tV, dtv, nsv);
    pack_kernel<<<256, 256, 0, stream>>>(W1, V1, W2, V2, packedW);
    sde_kernel<<<NP / 64, 256, 0, stream>>>(z0, pctx, cctx, xi, packedW,
                                            W1, V1, b2, c2, W3, b3, V3, c3,
                                            tembW, tV, dtv, nsv,
                                            (float*)d_out);
}

// Round 8
// 637.497 us; speedup vs baseline: 16.1602x; 1.1150x over previous
//
#include <hip/hip_runtime.h>
#include <hip/hip_bf16.h>
#include <math.h>

#define NP 65536
#define HD 128
#define TSTEPS 50

typedef short bf16x8 __attribute__((ext_vector_type(8)));
typedef float f32x4 __attribute__((ext_vector_type(4)));
typedef float f32x2 __attribute__((ext_vector_type(2)));

__device__ __forceinline__ short f2bf(float f) {
    union { float f; unsigned u; } v; v.f = f;
    unsigned r = v.u + 0x7fffu + ((v.u >> 16) & 1u);
    return (short)(r >> 16);
}
// packed pair -> one dword of 2 bf16 (low = a, high = b)
__device__ __forceinline__ unsigned cvt_pk_bf16(float a, float b) {
    __hip_bfloat162 h = __float22bfloat162_rn(make_float2(a, b));
    unsigned u;
    __builtin_memcpy(&u, &h, sizeof(u));
    return u;
}

// ---- packed fp32 math expressed as C vector ops: the backend selects
// v_pk_{fma,add,mul}_f32 on gfx950 (PackedFP32Ops); semantics guaranteed.
// (Hand-written VOP3P inline asm was the R6/R7 NaN source.)
__device__ __forceinline__ f32x2 pk_fma(f32x2 a, f32x2 b, f32x2 c) {
    return __builtin_elementwise_fma(a, b, c);
}
__device__ __forceinline__ f32x2 pk_add(f32x2 a, f32x2 b) { return a + b; }
__device__ __forceinline__ f32x2 pk_mul(f32x2 a, f32x2 b) { return a * b; }

// packed tanh: 1 - 2/(exp2(2x*log2e)+1); saturates via inf/0, no clamps
__device__ __forceinline__ f32x2 tanh_pk(f32x2 x, f32x2 k2, f32x2 one2, f32x2 m2) {
    f32x2 t = pk_mul(x, k2);
    f32x2 e;
    e.x = __builtin_amdgcn_exp2f(t.x);
    e.y = __builtin_amdgcn_exp2f(t.y);
    f32x2 dn = pk_add(e, one2);
    f32x2 r;
    r.x = __builtin_amdgcn_rcpf(dn.x);
    r.y = __builtin_amdgcn_rcpf(dn.y);
    return pk_fma(r, m2, one2);
}
__device__ __forceinline__ f32x2 shfl_xor_f2(f32x2 v, int off) {
    f32x2 d;
    d.x = __shfl_xor(v.x, off);
    d.y = __shfl_xor(v.y, off);
    return d;
}

// ---------------------------------------------------------------------------
// Per-step tables; one block per step i.
// ---------------------------------------------------------------------------
__global__ __launch_bounds__(128) void prep_kernel(
    const float* __restrict__ times, const float* __restrict__ freqs,
    const float* __restrict__ log_diff,
    const float* __restrict__ W1, const float* __restrict__ b1,
    const float* __restrict__ V1, const float* __restrict__ c1,
    float* __restrict__ tembW, float* __restrict__ tV,
    float* __restrict__ dtv, float* __restrict__ nsv)
{
    int j = threadIdx.x;
    int i = blockIdx.x;
    float ld = log_diff[0];
    float gb = (ld > 20.0f) ? ld : log1pf(expf(ld));  // softplus
    float t  = times[i];
    float dt = times[i + 1] - t;
    float acc = b1[j];
    #pragma unroll
    for (int m = 0; m < 16; ++m) {
        float a = 6.283185307179586f * t * freqs[m];
        float sn, cs;
        sincosf(a, &sn, &cs);
        acc = fmaf(sn, W1[(130 + m) * HD + j], acc);
        acc = fmaf(cs, W1[(146 + m) * HD + j], acc);
    }
    tembW[i * HD + j] = acc;
    tV[i * HD + j] = fmaf(t, V1[130 * HD + j], c1[j]);
    if (j == 0) {
        dtv[i] = dt;
        nsv[i] = gb * (1.0f - t) * sqrtf(fmaxf(dt, 1e-12f));
    }
}

// ---------------------------------------------------------------------------
// Pack 4 weight matrices (W1ctx, V1ctx, W2, V2) into bf16 B-fragment order:
// frag idx = ((jt*4+kt)*4+q)*16+c, element j;  k = kt*32+q*8+j, n = jt*16+c.
// ---------------------------------------------------------------------------
__global__ __launch_bounds__(256) void pack_kernel(
    const float* __restrict__ W1, const float* __restrict__ V1,
    const float* __restrict__ W2, const float* __restrict__ V2,
    short* __restrict__ packed)
{
    int gi = blockIdx.x * 256 + threadIdx.x;   // 0..65535
    int mat = gi >> 14;
    int s = gi & 16383;
    int j  = s & 7;
    int cc = (s >> 3) & 15;
    int qq = (s >> 7) & 3;
    int kt = (s >> 9) & 3;
    int jt = (s >> 11) & 7;
    int k = kt * 32 + qq * 8 + j;
    int n = jt * 16 + cc;
    float v;
    if      (mat == 0) v = W1[(2 + k) * HD + n];
    else if (mat == 1) v = V1[(2 + k) * HD + n];
    else if (mat == 2) v = W2[k * HD + n];
    else               v = V2[k * HD + n];
    packed[gi] = f2bf(v);
}

// ---------------------------------------------------------------------------
// Persistent SDE kernel: wave owns 16 particles (M=16 MFMA row tile) for all
// 50 steps.  Lane computes H1 directly in A-operand layout (m=lane&15,
// k=quad*8+j) -> no transform between layer1 and layer2 MFMA.
// R8: packed math via C ext-vector ops (backend selects v_pk_*_f32).
// ---------------------------------------------------------------------------
__global__ __launch_bounds__(256, 2) void sde_kernel(
    const float* __restrict__ z0, const float* __restrict__ pctx,
    const float* __restrict__ cctx, const float* __restrict__ xi,
    const short* __restrict__ packedW,
    const float* __restrict__ W1, const float* __restrict__ V1,
    const float* __restrict__ b2, const float* __restrict__ c2,
    const float* __restrict__ W3, const float* __restrict__ b3,
    const float* __restrict__ V3, const float* __restrict__ c3,
    const float* __restrict__ tembW, const float* __restrict__ tV,
    const float* __restrict__ dtv, const float* __restrict__ nsv,
    float* __restrict__ out)
{
    __shared__ char smem[80896];            // 66K frag/stg + 5K tables + 8K tslots
    float* stg = (float*)smem;
    const bf16x8* ldsF = (const bf16x8*)smem;
    float*  zwP0s = (float*)(smem + 67584);   // W1 row0 (z.x weights), fp32
    float*  zwP1s = (float*)(smem + 68096);   // W1 row1
    float*  zwC0s = (float*)(smem + 68608);   // V1 row0
    float*  zwC1s = (float*)(smem + 69120);   // V1 row1
    float*  b2s   = (float*)(smem + 69632);
    float*  c2s   = (float*)(smem + 70144);
    float2* w3s   = (float2*)(smem + 70656);
    float2* v3s   = (float2*)(smem + 71680);

    int tid = threadIdx.x;
    int lane = tid & 63, wv = tid >> 6;
    int q = lane >> 4, c = lane & 15;
    int m0 = blockIdx.x * 64 + wv * 16;     // wave's 16-row base
    int mrow = m0 + c;                      // this lane's A-layout row

    // per-wave table slot: 2 buffers x 256 floats (tV[0:128] ++ tembW[128:256])
    float* tslot = (float*)(smem + 72704) + wv * 512;

    // ---- small constant tables -> LDS (covered by the phase-1 barrier) ----
    if (tid < 128) {
        zwP0s[tid] = W1[tid];
        zwP1s[tid] = W1[HD + tid];
        zwC0s[tid] = V1[tid];
        zwC1s[tid] = V1[HD + tid];
        b2s[tid] = b2[tid];
        c2s[tid] = c2[tid];
        w3s[tid] = ((const float2*)W3)[tid];
        v3s[tid] = ((const float2*)V3)[tid];
    }

    // ---- phase 1: W1ctx/V1ctx fragments -> LDS (coalesced copy) ----
    {
        const uint4* src = (const uint4*)packedW;   // mats 0,1 = 64 KB
        uint4* dst = (uint4*)smem;
        #pragma unroll
        for (int i = 0; i < 16; ++i) dst[i * 256 + tid] = src[i * 256 + tid];
    }
    __syncthreads();

    // ---- ctx A-fragments ----
    bf16x8 pf[4], cf[4];
    #pragma unroll
    for (int kt = 0; kt < 4; ++kt) {
        const float4* p4 = (const float4*)(pctx + (size_t)mrow * HD + kt * 32 + q * 8);
        float4 a = p4[0], b = p4[1];
        uint4 tu;
        tu.x = cvt_pk_bf16(a.x, a.y); tu.y = cvt_pk_bf16(a.z, a.w);
        tu.z = cvt_pk_bf16(b.x, b.y); tu.w = cvt_pk_bf16(b.z, b.w);
        __builtin_memcpy(&pf[kt], &tu, 16);
        const float4* c4 = (const float4*)(cctx + (size_t)mrow * HD + kt * 32 + q * 8);
        float4 e = c4[0], d = c4[1];
        uint4 uu;
        uu.x = cvt_pk_bf16(e.x, e.y); uu.y = cvt_pk_bf16(e.z, e.w);
        uu.z = cvt_pk_bf16(d.x, d.y); uu.w = cvt_pk_bf16(d.z, d.w);
        __builtin_memcpy(&cf[kt], &uu, 16);
    }

    // ---- ctx projection MFMAs (step-invariant) ----
    f32x4 accP[8], accC[8];
    #pragma unroll
    for (int jt = 0; jt < 8; ++jt) {
        f32x4 ap = {0.f,0.f,0.f,0.f}, ac = {0.f,0.f,0.f,0.f};
        #pragma unroll
        for (int kt = 0; kt < 4; ++kt) {
            int fi = ((jt * 4 + kt) * 4 + q) * 16 + c;
            ap = __builtin_amdgcn_mfma_f32_16x16x32_bf16(pf[kt], ldsF[fi], ap, 0, 0, 0);
            ac = __builtin_amdgcn_mfma_f32_16x16x32_bf16(cf[kt], ldsF[2048 + fi], ac, 0, 0, 0);
        }
        accP[jt] = ap; accC[jt] = ac;
    }
    __syncthreads();

    // ---- C-layout -> A-layout round trip through LDS (once) ----
    #pragma unroll
    for (int jt = 0; jt < 8; ++jt)
        #pragma unroll
        for (int r = 0; r < 4; ++r) {
            stg[(wv * 16 + q * 4 + r) * 132 + jt * 16 + c]        = accP[jt][r];
            stg[8448 + (wv * 16 + q * 4 + r) * 132 + jt * 16 + c] = accC[jt][r];
        }
    __syncthreads();
    f32x2 projPf[16], projCf[16];   // fp32 pairs (no per-step unpack)
    #pragma unroll
    for (int kt = 0; kt < 4; ++kt) {
        const float4* rp = (const float4*)(stg + (wv * 16 + c) * 132 + kt * 32 + q * 8);
        float4 a = rp[0], b = rp[1];
        projPf[kt*4+0] = (f32x2){a.x, a.y}; projPf[kt*4+1] = (f32x2){a.z, a.w};
        projPf[kt*4+2] = (f32x2){b.x, b.y}; projPf[kt*4+3] = (f32x2){b.z, b.w};
        const float4* rc = (const float4*)(stg + 8448 + (wv * 16 + c) * 132 + kt * 32 + q * 8);
        float4 e = rc[0], d = rc[1];
        projCf[kt*4+0] = (f32x2){e.x, e.y}; projCf[kt*4+1] = (f32x2){e.z, e.w};
        projCf[kt*4+2] = (f32x2){d.x, d.y}; projCf[kt*4+3] = (f32x2){d.z, d.w};
    }
    __syncthreads();

    // ---- phase 3: W2/V2 fragments -> LDS (resident for all 50 steps) ----
    {
        const uint4* src = (const uint4*)(packedW + 32768);  // mats 2,3
        uint4* dst = (uint4*)smem;
        #pragma unroll
        for (int i = 0; i < 16; ++i) dst[i * 256 + tid] = src[i * 256 + tid];
    }
    __syncthreads();

    float b3x = b3[0] + c3[0], b3y = b3[1] + c3[1];
    const f32x2 k2   = {2.8853900817779268f, 2.8853900817779268f};
    const f32x2 one2 = {1.0f, 1.0f};
    const f32x2 m2   = {-2.0f, -2.0f};

    const float2* z02 = (const float2*)z0;
    const float2* xi2 = (const float2*)xi;
    float2* out2 = (float2*)out;

    // ---- stage step-0 tables into buf 0 (wave-private, no barrier) ----
    {
        const float4* srcp = (lane < 32)
            ? ((const float4*)(tV) + lane)
            : ((const float4*)(tembW) + (lane - 32));
        *((float4*)tslot + lane) = *srcp;
    }

    float2 zi = z02[mrow];
    float zx = zi.x, zy = zi.y;          // z for row m = c (A-layout row)
    int row_mine = q * 4 + (c & 3);      // row whose update this lane computes
    if (lane < 16) out2[m0 + lane] = make_float2(zx, zy);   // lane l holds row l

    for (int i = 0; i < TSTEPS; ++i) {
        int b = i & 1;
        const float* tb = tslot + b * 256;

        // prefetch next step's table slice (consumed at end of step)
        int sN = (i + 1 < TSTEPS) ? i + 1 : i;
        float4 pfv;
        {
            const float4* srcp = (lane < 32)
                ? ((const float4*)(tV + sN * HD) + lane)
                : ((const float4*)(tembW + sN * HD) + (lane - 32));
            pfv = *srcp;
        }
        // xi + step scalars, hoisted
        float dt = dtv[i], ns = nsv[i];
        float2 xiv = xi2[(size_t)i * NP + m0 + row_mine];

        f32x2 zx2 = {zx, zx}, zy2 = {zy, zy};
        f32x2 px01 = {b3x, b3x}, px23 = px01;
        f32x2 py01 = {b3y, b3y}, py23 = py01;

        // ===== cnf MLP: tanh, V-weights (LDS slot 1) =====
        bf16x8 af[4];
        #pragma unroll
        for (int kt = 0; kt < 4; ++kt) {
            const f32x2* tvp = (const f32x2*)(tb + kt * 32 + q * 8);
            const f32x2* w0p = (const f32x2*)(zwC0s + kt * 32 + q * 8);
            const f32x2* w1p = (const f32x2*)(zwC1s + kt * 32 + q * 8);
            uint4 tu;
            unsigned uu[4];
            #pragma unroll
            for (int p = 0; p < 4; ++p) {
                f32x2 lin = pk_add(projCf[kt * 4 + p], tvp[p]);
                lin = pk_fma(zx2, w0p[p], lin);
                lin = pk_fma(zy2, w1p[p], lin);
                f32x2 th = tanh_pk(lin, k2, one2, m2);
                uu[p] = cvt_pk_bf16(th.x, th.y);
            }
            tu.x = uu[0]; tu.y = uu[1]; tu.z = uu[2]; tu.w = uu[3];
            __builtin_memcpy(&af[kt], &tu, 16);
        }
        #pragma unroll
        for (int jt = 0; jt < 8; ++jt) {
            float cb = c2s[jt * 16 + c];
            f32x4 acc = {cb, cb, cb, cb};
            #pragma unroll
            for (int kt = 0; kt < 4; ++kt)
                acc = __builtin_amdgcn_mfma_f32_16x16x32_bf16(
                    af[kt], ldsF[2048 + ((jt * 4 + kt) * 4 + q) * 16 + c], acc, 0, 0, 0);
            f32x2 a01 = {acc[0], acc[1]};
            f32x2 a23 = {acc[2], acc[3]};
            f32x2 h01 = tanh_pk(a01, k2, one2, m2);
            f32x2 h23 = tanh_pk(a23, k2, one2, m2);
            float2 v3 = v3s[jt * 16 + c];
            f32x2 v3x = {v3.x, v3.x}, v3y = {v3.y, v3.y};
            px01 = pk_fma(h01, v3x, px01); px23 = pk_fma(h23, v3x, px23);
            py01 = pk_fma(h01, v3y, py01); py23 = pk_fma(h23, v3y, py23);
        }

        // ===== post MLP: relu, W-weights (LDS slot 0) =====
        #pragma unroll
        for (int kt = 0; kt < 4; ++kt) {
            const f32x2* tvp = (const f32x2*)(tb + 128 + kt * 32 + q * 8);
            const f32x2* w0p = (const f32x2*)(zwP0s + kt * 32 + q * 8);
            const f32x2* w1p = (const f32x2*)(zwP1s + kt * 32 + q * 8);
            uint4 tu;
            unsigned uu[4];
            #pragma unroll
            for (int p = 0; p < 4; ++p) {
                f32x2 lin = pk_add(projPf[kt * 4 + p], tvp[p]);
                lin = pk_fma(zx2, w0p[p], lin);
                lin = pk_fma(zy2, w1p[p], lin);
                f32x2 th;
                th.x = fmaxf(lin.x, 0.0f);
                th.y = fmaxf(lin.y, 0.0f);
                uu[p] = cvt_pk_bf16(th.x, th.y);
            }
            tu.x = uu[0]; tu.y = uu[1]; tu.z = uu[2]; tu.w = uu[3];
            __builtin_memcpy(&af[kt], &tu, 16);
        }
        #pragma unroll
        for (int jt = 0; jt < 8; ++jt) {
            float bb = b2s[jt * 16 + c];
            f32x4 acc = {bb, bb, bb, bb};
            #pragma unroll
            for (int kt = 0; kt < 4; ++kt)
                acc = __builtin_amdgcn_mfma_f32_16x16x32_bf16(
                    af[kt], ldsF[((jt * 4 + kt) * 4 + q) * 16 + c], acc, 0, 0, 0);
            f32x2 h01, h23;
            h01.x = fmaxf(acc[0], 0.0f); h01.y = fmaxf(acc[1], 0.0f);
            h23.x = fmaxf(acc[2], 0.0f); h23.y = fmaxf(acc[3], 0.0f);
            float2 w3 = w3s[jt * 16 + c];
            f32x2 w3x = {w3.x, w3.x}, w3y = {w3.y, w3.y};
            px01 = pk_fma(h01, w3x, px01); px23 = pk_fma(h23, w3x, px23);
            py01 = pk_fma(h01, w3y, py01); py23 = pk_fma(h23, w3y, py23);
        }

        // write prefetched tables to the other buffer (global load had the
        // whole step to land; next iteration's ds_reads sync via lgkmcnt)
        *((float4*)(tslot + (b ^ 1) * 256) + lane) = pfv;

        // ===== reduce over the 16-lane column groups =====
        #pragma unroll
        for (int off = 1; off < 16; off <<= 1) {
            px01 = pk_add(px01, shfl_xor_f2(px01, off));
            px23 = pk_add(px23, shfl_xor_f2(px23, off));
            py01 = pk_add(py01, shfl_xor_f2(py01, off));
            py23 = pk_add(py23, shfl_xor_f2(py23, off));
        }

        // ===== z update: every lane computes its row_mine =====
        int cc = c & 3;
        float sdx = px01.x, sdy = py01.x;
        sdx = (cc == 1) ? px01.y : sdx; sdy = (cc == 1) ? py01.y : sdy;
        sdx = (cc == 2) ? px23.x : sdx; sdy = (cc == 2) ? py23.x : sdy;
        sdx = (cc == 3) ? px23.y : sdx; sdy = (cc == 3) ? py23.y : sdy;
        float zox = __shfl(zx, row_mine), zoy = __shfl(zy, row_mine);
        float znx = fmaf(sdx, dt, zox) + xiv.x * ns;
        float zny = fmaf(sdy, dt, zoy) + xiv.y * ns;

        // coalesced store: lanes 0..15 hold rows 0..15 after one shfl
        int src_store = ((lane >> 2) << 4) | (lane & 3);
        float sx = __shfl(znx, src_store);
        float sy = __shfl(zny, src_store);
        if (lane < 16) out2[(size_t)(i + 1) * NP + m0 + lane] = make_float2(sx, sy);

        // re-broadcast z for next step's A-layout (lane holds row c)
        int src_z = ((c >> 2) << 4) | (c & 3);
        zx = __shfl(znx, src_z);
        zy = __shfl(zny, src_z);
    }
}

extern "C" void kernel_launch(void* const* d_in, const int* in_sizes, int n_in,
                              void* d_out, int out_size, void* d_ws, size_t ws_size,
                              hipStream_t stream)
{
    const float* z0    = (const float*)d_in[0];
    const float* pctx  = (const float*)d_in[1];
    const float* cctx  = (const float*)d_in[2];
    const float* times = (const float*)d_in[3];
    const float* xi    = (const float*)d_in[4];
    const float* freqs = (const float*)d_in[5];
    const float* logd  = (const float*)d_in[6];
    const float* W1 = (const float*)d_in[7];
    const float* b1 = (const float*)d_in[8];
    const float* W2 = (const float*)d_in[9];
    const float* b2 = (const float*)d_in[10];
    const float* W3 = (const float*)d_in[11];
    const float* b3 = (const float*)d_in[12];
    const float* V1 = (const float*)d_in[13];
    const float* c1 = (const float*)d_in[14];
    const float* V2 = (const float*)d_in[15];
    const float* c2 = (const float*)d_in[16];
    const float* V3 = (const float*)d_in[17];
    const float* c3 = (const float*)d_in[18];

    short* packedW = (short*)d_ws;                       // 4 x 16384 shorts = 128 KB
    float* tembW = (float*)((char*)d_ws + 131072);       // [50][128]
    float* tV    = tembW + TSTEPS * HD;                  // [50][128]
    float* dtv   = tV + TSTEPS * HD;
    float* nsv   = dtv + 64;

    prep_kernel<<<TSTEPS, 128, 0, stream>>>(times, freqs, logd, W1, b1, V1, c1,
                                            tembW, tV, dtv, nsv);
    pack_kernel<<<256, 256, 0, stream>>>(W1, V1, W2, V2, packedW);
    sde_kernel<<<NP / 64, 256, 0, stream>>>(z0, pctx, cctx, xi, packedW,
                                            W1, V1, b2, c2, W3, b3, V3, c3,
                                            tembW, tV, dtv, nsv,
                                            (float*)d_out);
}